// Round 1
// baseline (791.616 us; speedup 1.0000x reference)
//
#include <hip/hip_runtime.h>
#include <hip/hip_bf16.h>
#include <stdint.h>

#define N_TOK 2048
#define DM    2048
#define NEXP  64
#define TOPK  4
#define HEXP  512
#define CAPC  512
#define NSH   2
#define HSH   2048
#define RTB   8

typedef __attribute__((ext_vector_type(8))) short short8;
typedef __attribute__((ext_vector_type(4))) short short4v;
typedef __attribute__((ext_vector_type(4))) float f32x4;
typedef __attribute__((ext_vector_type(4))) float f4;

static __device__ __forceinline__ unsigned short f2bf(float f) {
  union { float f; unsigned u; } v; v.f = f;
  unsigned r = v.u + 0x7FFFu + ((v.u >> 16) & 1u);   // RNE
  return (unsigned short)(r >> 16);
}

// ---------------------------------------------------------------- convert x
__global__ __launch_bounds__(256) void k_convert(const float* __restrict__ x,
                                                 unsigned short* __restrict__ xb) {
  int i = (blockIdx.x * 256 + threadIdx.x) * 8;
  f4 a = *(const f4*)(x + i);
  f4 b = *(const f4*)(x + i + 4);
  short8 o;
  o[0]=f2bf(a[0]); o[1]=f2bf(a[1]); o[2]=f2bf(a[2]); o[3]=f2bf(a[3]);
  o[4]=f2bf(b[0]); o[5]=f2bf(b[1]); o[6]=f2bf(b[2]); o[7]=f2bf(b[3]);
  *(short8*)(xb + i) = o;
}

// ---------------------------------------------------------------- router
#define ARGMAX_ROUND(S,I)                                            \
  { float bv = v; int bi = lane;                                     \
    _Pragma("unroll")                                                \
    for (int o = 32; o; o >>= 1) {                                   \
      float ov = __shfl_xor(bv, o); int oi = __shfl_xor(bi, o);      \
      if (ov > bv || (ov == bv && oi < bi)) { bv = ov; bi = oi; }    \
    }                                                                \
    S = bv; I = bi; if (lane == bi) v = -1.f; }

__global__ __launch_bounds__(256) void k_router(const float* __restrict__ x,
    const float* __restrict__ Wr, const float* __restrict__ bias,
    int* __restrict__ cnt, int* __restrict__ lists, float* __restrict__ wlist) {
  __shared__ float part[4][RTB][64];
  __shared__ float logits[RTB][64];
  int t = threadIdx.x;
  int e = t & 63, sl = t >> 6;
  int tok0 = blockIdx.x * RTB;
  const float* xp = x + (size_t)tok0 * DM;
  float acc[RTB];
#pragma unroll
  for (int i = 0; i < RTB; ++i) acc[i] = 0.f;
  for (int d = sl * 512; d < sl * 512 + 512; ++d) {
    float w = Wr[(size_t)d * NEXP + e];
#pragma unroll
    for (int i = 0; i < RTB; ++i) acc[i] += xp[(size_t)i * DM + d] * w;
  }
#pragma unroll
  for (int i = 0; i < RTB; ++i) part[sl][i][e] = acc[i];
  __syncthreads();
  for (int i = sl; i < RTB; i += 4)
    logits[i][e] = part[0][i][e] + part[1][i][e] + part[2][i][e] + part[3][i][e] + bias[e];
  __syncthreads();
  int lane = t & 63, wv = t >> 6;
  for (int i = wv * 2; i < wv * 2 + 2; ++i) {
    float lg = logits[i][lane];
    float m = lg;
#pragma unroll
    for (int o = 32; o; o >>= 1) m = fmaxf(m, __shfl_xor(m, o));
    float p = expf(lg - m);
    float sm = p;
#pragma unroll
    for (int o = 32; o; o >>= 1) sm += __shfl_xor(sm, o);
    float v = p / sm;
    float s0, s1, s2, s3; int i0, i1, i2, i3;
    ARGMAX_ROUND(s0, i0)
    ARGMAX_ROUND(s1, i1)
    ARGMAX_ROUND(s2, i2)
    ARGMAX_ROUND(s3, i3)
    float tot = s0 + s1 + s2 + s3;
    if (lane < TOPK) {
      float myw = (lane == 0 ? s0 : lane == 1 ? s1 : lane == 2 ? s2 : s3) / tot;
      int   mye = (lane == 0 ? i0 : lane == 1 ? i1 : lane == 2 ? i2 : i3);
      int pos = atomicAdd(&cnt[mye], 1);
      if (pos < CAPC) {
        lists[mye * CAPC + pos] = tok0 + i;
        wlist[mye * CAPC + pos] = myw;
      }
    }
  }
}

// ---------------------------------------------------------------- offsets
__global__ void k_offs(const int* __restrict__ cnt, int* __restrict__ offs) {
  int l = threadIdx.x;            // 64 threads
  int c = min(cnt[l], CAPC);
  int sum = c;
#pragma unroll
  for (int o = 1; o < 64; o <<= 1) {
    int ov = __shfl_up(sum, o);
    if (l >= o) sum += ov;
  }
  offs[l + 1] = sum;
  if (l == 0) offs[0] = 0;
}

// ---------------------------------------------------------------- GEMM pieces
// LDS tiles: A [128][64] bf16 (row-major, 128B rows), B [64 n][64 k] bf16.
// XOR swizzle: byte ^= (row&7)<<4  (both write and read sides).

template<bool GATHER>
static __device__ __forceinline__ void stageA(const unsigned short* __restrict__ src,
    int lda, int m0, int Mvalid, const int* __restrict__ gl,
    unsigned short* lA, int k0) {
  int tid = threadIdx.x;
#pragma unroll
  for (int p = 0; p < 4; ++p) {
    int idx = p * 256 + tid;
    int row = idx >> 3;
    int ko  = (idx & 7) * 8;
    short8 val;
    int grow = m0 + row;
    if (grow < Mvalid) {
      int srow = GATHER ? gl[grow] : grow;
      val = *(const short8*)(src + (size_t)srow * lda + k0 + ko);
    } else {
#pragma unroll
      for (int j = 0; j < 8; ++j) val[j] = 0;
    }
    int byte = row * 128 + ko * 2;
    byte ^= (row & 7) << 4;
    *(short8*)((char*)lA + byte) = val;
  }
}

static __device__ __forceinline__ void stageB(const float* __restrict__ B, int ldb,
    int k0, int n0, unsigned short* lB) {
  int tid = threadIdx.x;
  int kb = tid >> 4;               // k block of 4
  int nb = tid & 15;               // n block of 4
  const float* p = B + (size_t)(k0 + kb * 4) * ldb + n0 + nb * 4;
  f4 r0 = *(const f4*)(p);
  f4 r1 = *(const f4*)(p + ldb);
  f4 r2 = *(const f4*)(p + 2 * (size_t)ldb);
  f4 r3 = *(const f4*)(p + 3 * (size_t)ldb);
#pragma unroll
  for (int c = 0; c < 4; ++c) {
    short4v vv;
    vv[0] = (short)f2bf(r0[c]); vv[1] = (short)f2bf(r1[c]);
    vv[2] = (short)f2bf(r2[c]); vv[3] = (short)f2bf(r3[c]);
    int n = nb * 4 + c;
    int byte = n * 128 + kb * 8;
    byte ^= (n & 7) << 4;
    *(short4v*)((char*)lB + byte) = vv;
  }
}

static __device__ __forceinline__ short8 frag_ld(const unsigned short* lds, int row, int kElem) {
  int byte = row * 128 + kElem * 2;
  byte ^= (row & 7) << 4;
  return *(const short8*)((const char*)lds + byte);
}

static __device__ __forceinline__ void mma1(const unsigned short* lA, const unsigned short* lB,
    f32x4 (&acc)[4][2], int wm, int wn, int lane) {
  int r16 = lane & 15;
  int kg  = (lane >> 4) * 8;
#pragma unroll
  for (int kk = 0; kk < 2; ++kk) {
    int kb = kk * 32 + kg;
    short8 a[4], b[2];
#pragma unroll
    for (int mf = 0; mf < 4; ++mf) a[mf] = frag_ld(lA, wm + mf * 16 + r16, kb);
#pragma unroll
    for (int nf = 0; nf < 2; ++nf) b[nf] = frag_ld(lB, wn + nf * 16 + r16, kb);
#pragma unroll
    for (int mf = 0; mf < 4; ++mf)
#pragma unroll
      for (int nf = 0; nf < 2; ++nf)
        acc[mf][nf] = __builtin_amdgcn_mfma_f32_16x16x32_bf16(a[mf], b[nf], acc[mf][nf], 0, 0, 0);
  }
}

static __device__ __forceinline__ void mma2(const unsigned short* lA,
    const unsigned short* lBg, const unsigned short* lBu,
    f32x4 (&accg)[4][2], f32x4 (&accu)[4][2], int wm, int wn, int lane) {
  int r16 = lane & 15;
  int kg  = (lane >> 4) * 8;
#pragma unroll
  for (int kk = 0; kk < 2; ++kk) {
    int kb = kk * 32 + kg;
    short8 a[4], bg[2], bu[2];
#pragma unroll
    for (int mf = 0; mf < 4; ++mf) a[mf] = frag_ld(lA, wm + mf * 16 + r16, kb);
#pragma unroll
    for (int nf = 0; nf < 2; ++nf) {
      bg[nf] = frag_ld(lBg, wn + nf * 16 + r16, kb);
      bu[nf] = frag_ld(lBu, wn + nf * 16 + r16, kb);
    }
#pragma unroll
    for (int mf = 0; mf < 4; ++mf)
#pragma unroll
      for (int nf = 0; nf < 2; ++nf) {
        accg[mf][nf] = __builtin_amdgcn_mfma_f32_16x16x32_bf16(a[mf], bg[nf], accg[mf][nf], 0, 0, 0);
        accu[mf][nf] = __builtin_amdgcn_mfma_f32_16x16x32_bf16(a[mf], bu[nf], accu[mf][nf], 0, 0, 0);
      }
  }
}

static __device__ __forceinline__ float silu_mul(float g, float u) {
  return g / (1.f + expf(-g)) * u;
}

// ---------------------------------------------------------------- expert gate+up
__global__ __launch_bounds__(256) void k_expert_gateup(const unsigned short* __restrict__ xbf,
    const float* __restrict__ Wg, const float* __restrict__ Wu,
    const int* __restrict__ cnt, const int* __restrict__ offs,
    const int* __restrict__ lists, unsigned short* __restrict__ hws) {
  int e = blockIdx.y;
  int ne = min(cnt[e], CAPC);
  if (ne == 0) return;
  int n0 = blockIdx.x * 64;
  const float* Bg = Wg + (size_t)e * DM * HEXP;
  const float* Bu = Wu + (size_t)e * DM * HEXP;
  const int* lst = lists + e * CAPC;
  int base = offs[e];
  __shared__ unsigned short lA[128 * 64];
  __shared__ unsigned short lBg[64 * 64];
  __shared__ unsigned short lBu[64 * 64];
  int lane = threadIdx.x & 63, wv = threadIdx.x >> 6;
  int wm = (wv >> 1) * 64, wn = (wv & 1) * 32;
  for (int m0 = 0; m0 < ne; m0 += 128) {
    f32x4 accg[4][2] = {};
    f32x4 accu[4][2] = {};
    for (int k0 = 0; k0 < DM; k0 += 64) {
      stageA<true>(xbf, DM, m0, ne, lst, lA, k0);
      stageB(Bg, HEXP, k0, n0, lBg);
      stageB(Bu, HEXP, k0, n0, lBu);
      __syncthreads();
      mma2(lA, lBg, lBu, accg, accu, wm, wn, lane);
      __syncthreads();
    }
#pragma unroll
    for (int mf = 0; mf < 4; ++mf)
#pragma unroll
      for (int r = 0; r < 4; ++r) {
        int rl = m0 + wm + mf * 16 + (lane >> 4) * 4 + r;
        if (rl < ne) {
#pragma unroll
          for (int nf = 0; nf < 2; ++nf) {
            int col = n0 + wn + nf * 16 + (lane & 15);
            float h = silu_mul(accg[mf][nf][r], accu[mf][nf][r]);
            hws[(size_t)(base + rl) * HEXP + col] = f2bf(h);
          }
        }
      }
  }
}

// ---------------------------------------------------------------- shared gate+up
__global__ __launch_bounds__(256) void k_shared_gateup(const unsigned short* __restrict__ xbf,
    const float* __restrict__ Sg, const float* __restrict__ Su,
    unsigned short* __restrict__ hs) {
  int n0 = blockIdx.x * 64;
  int m0 = blockIdx.y * 128;
  int s  = blockIdx.z;
  const float* Bg = Sg + (size_t)s * DM * HSH;
  const float* Bu = Su + (size_t)s * DM * HSH;
  __shared__ unsigned short lA[128 * 64];
  __shared__ unsigned short lBg[64 * 64];
  __shared__ unsigned short lBu[64 * 64];
  int lane = threadIdx.x & 63, wv = threadIdx.x >> 6;
  int wm = (wv >> 1) * 64, wn = (wv & 1) * 32;
  f32x4 accg[4][2] = {};
  f32x4 accu[4][2] = {};
  for (int k0 = 0; k0 < DM; k0 += 64) {
    stageA<false>(xbf, DM, m0, N_TOK, nullptr, lA, k0);
    stageB(Bg, HSH, k0, n0, lBg);
    stageB(Bu, HSH, k0, n0, lBu);
    __syncthreads();
    mma2(lA, lBg, lBu, accg, accu, wm, wn, lane);
    __syncthreads();
  }
#pragma unroll
  for (int mf = 0; mf < 4; ++mf)
#pragma unroll
    for (int nf = 0; nf < 2; ++nf)
#pragma unroll
      for (int r = 0; r < 4; ++r) {
        int row = m0 + wm + mf * 16 + (lane >> 4) * 4 + r;
        int col = n0 + wn + nf * 16 + (lane & 15);
        float h = silu_mul(accg[mf][nf][r], accu[mf][nf][r]);
        hs[(size_t)row * (NSH * HSH) + s * HSH + col] = f2bf(h);
      }
}

// ---------------------------------------------------------------- shared down (writes out)
__global__ __launch_bounds__(256) void k_shared_down(const unsigned short* __restrict__ hs,
    const float* __restrict__ Sd, float* __restrict__ out) {
  int n0 = blockIdx.x * 64;
  int m0 = blockIdx.y * 128;
  __shared__ unsigned short lA[128 * 64];
  __shared__ unsigned short lB[64 * 64];
  int lane = threadIdx.x & 63, wv = threadIdx.x >> 6;
  int wm = (wv >> 1) * 64, wn = (wv & 1) * 32;
  f32x4 acc[4][2] = {};
  for (int k0 = 0; k0 < NSH * HSH; k0 += 64) {
    stageA<false>(hs, NSH * HSH, m0, N_TOK, nullptr, lA, k0);
    stageB(Sd, DM, k0, n0, lB);      // Sd viewed as [4096][2048]
    __syncthreads();
    mma1(lA, lB, acc, wm, wn, lane);
    __syncthreads();
  }
#pragma unroll
  for (int mf = 0; mf < 4; ++mf)
#pragma unroll
    for (int nf = 0; nf < 2; ++nf)
#pragma unroll
      for (int r = 0; r < 4; ++r) {
        int row = m0 + wm + mf * 16 + (lane >> 4) * 4 + r;
        int col = n0 + wn + nf * 16 + (lane & 15);
        out[(size_t)row * DM + col] = acc[mf][nf][r];
      }
}

// ---------------------------------------------------------------- expert down (atomic add)
__global__ __launch_bounds__(256) void k_expert_down(const unsigned short* __restrict__ hws,
    const float* __restrict__ Wd, const int* __restrict__ cnt, const int* __restrict__ offs,
    const int* __restrict__ lists, const float* __restrict__ wlist,
    float* __restrict__ out) {
  int e = blockIdx.y;
  int ne = min(cnt[e], CAPC);
  if (ne == 0) return;
  int n0 = blockIdx.x * 64;
  const float* B = Wd + (size_t)e * HEXP * DM;
  const unsigned short* A = hws + (size_t)offs[e] * HEXP;
  __shared__ unsigned short lA[128 * 64];
  __shared__ unsigned short lB[64 * 64];
  int lane = threadIdx.x & 63, wv = threadIdx.x >> 6;
  int wm = (wv >> 1) * 64, wn = (wv & 1) * 32;
  for (int m0 = 0; m0 < ne; m0 += 128) {
    f32x4 acc[4][2] = {};
    for (int k0 = 0; k0 < HEXP; k0 += 64) {
      stageA<false>(A, HEXP, m0, ne, nullptr, lA, k0);
      stageB(B, DM, k0, n0, lB);
      __syncthreads();
      mma1(lA, lB, acc, wm, wn, lane);
      __syncthreads();
    }
#pragma unroll
    for (int mf = 0; mf < 4; ++mf)
#pragma unroll
      for (int r = 0; r < 4; ++r) {
        int rl = m0 + wm + mf * 16 + (lane >> 4) * 4 + r;
        if (rl < ne) {
          int tok  = lists[e * CAPC + rl];
          float w  = wlist[e * CAPC + rl];
#pragma unroll
          for (int nf = 0; nf < 2; ++nf) {
            int col = n0 + wn + nf * 16 + (lane & 15);
            atomicAdd(out + (size_t)tok * DM + col, acc[mf][nf][r] * w);
          }
        }
      }
  }
}

// ---------------------------------------------------------------- launch
extern "C" void kernel_launch(void* const* d_in, const int* in_sizes, int n_in,
                              void* d_out, int out_size, void* d_ws, size_t ws_size,
                              hipStream_t stream) {
  const float* x    = (const float*)d_in[0];
  const float* Wr   = (const float*)d_in[1];
  const float* bias = (const float*)d_in[2];
  const float* Wg   = (const float*)d_in[3];
  const float* Wu   = (const float*)d_in[4];
  const float* Wd   = (const float*)d_in[5];
  const float* Sg   = (const float*)d_in[6];
  const float* Su   = (const float*)d_in[7];
  const float* Sd   = (const float*)d_in[8];
  float* out = (float*)d_out;
  char* ws = (char*)d_ws;

  const size_t off_cnt   = 0;
  const size_t off_offs  = 256;
  const size_t off_lists = 1024;
  const size_t off_wlist = off_lists + (size_t)NEXP * CAPC * 4;
  const size_t off_xbf   = off_wlist + (size_t)NEXP * CAPC * 4;
  const size_t off_hs    = off_xbf + (size_t)N_TOK * DM * 2;
  const size_t off_h     = off_hs + (size_t)N_TOK * NSH * HSH * 2;
  const size_t req       = off_h + (size_t)N_TOK * TOPK * HEXP * 2;
  if (ws_size < req) return;   // loud failure, no corruption

  int* cnt            = (int*)(ws + off_cnt);
  int* offs           = (int*)(ws + off_offs);
  int* lists          = (int*)(ws + off_lists);
  float* wlist        = (float*)(ws + off_wlist);
  unsigned short* xbf = (unsigned short*)(ws + off_xbf);
  unsigned short* hs  = (unsigned short*)(ws + off_hs);
  unsigned short* hws = (unsigned short*)(ws + off_h);

  hipMemsetAsync(cnt, 0, NEXP * sizeof(int), stream);
  k_convert<<<(N_TOK * DM) / (256 * 8), 256, 0, stream>>>(x, xbf);
  k_router<<<N_TOK / RTB, 256, 0, stream>>>(x, Wr, bias, cnt, lists, wlist);
  k_offs<<<1, 64, 0, stream>>>(cnt, offs);
  k_expert_gateup<<<dim3(HEXP / 64, NEXP), 256, 0, stream>>>(xbf, Wg, Wu, cnt, offs, lists, hws);
  k_shared_gateup<<<dim3(HSH / 64, N_TOK / 128, NSH), 256, 0, stream>>>(xbf, Sg, Su, hs);
  k_shared_down<<<dim3(DM / 64, N_TOK / 128), 256, 0, stream>>>(hs, Sd, out);
  k_expert_down<<<dim3(DM / 64, NEXP), 256, 0, stream>>>(hws, Wd, cnt, offs, lists, wlist, out);
}

// Round 2
// 669.377 us; speedup vs baseline: 1.1826x; 1.1826x over previous
//
#include <hip/hip_runtime.h>
#include <hip/hip_bf16.h>
#include <stdint.h>

#define N_TOK 2048
#define DM    2048
#define NEXP  64
#define TOPK  4
#define HEXP  512
#define CAPC  512
#define NSH   2
#define HSH   2048
#define RTB   8

typedef __attribute__((ext_vector_type(8))) short short8;
typedef __attribute__((ext_vector_type(4))) short short4v;
typedef __attribute__((ext_vector_type(4))) float f32x4;
typedef __attribute__((ext_vector_type(4))) float f4;

static __device__ __forceinline__ unsigned short f2bf(float f) {
  union { float f; unsigned u; } v; v.f = f;
  unsigned r = v.u + 0x7FFFu + ((v.u >> 16) & 1u);   // RNE
  return (unsigned short)(r >> 16);
}

// ---------------------------------------------------------------- convert x
__global__ __launch_bounds__(256) void k_convert(const float* __restrict__ x,
                                                 unsigned short* __restrict__ xb) {
  int i = (blockIdx.x * 256 + threadIdx.x) * 8;
  f4 a = *(const f4*)(x + i);
  f4 b = *(const f4*)(x + i + 4);
  short8 o;
  o[0]=f2bf(a[0]); o[1]=f2bf(a[1]); o[2]=f2bf(a[2]); o[3]=f2bf(a[3]);
  o[4]=f2bf(b[0]); o[5]=f2bf(b[1]); o[6]=f2bf(b[2]); o[7]=f2bf(b[3]);
  *(short8*)(xb + i) = o;
}

// ---------------------------------------------------------------- router
#define ARGMAX_ROUND(S,I)                                            \
  { float bv = v; int bi = lane;                                     \
    _Pragma("unroll")                                                \
    for (int o = 32; o; o >>= 1) {                                   \
      float ov = __shfl_xor(bv, o); int oi = __shfl_xor(bi, o);      \
      if (ov > bv || (ov == bv && oi < bi)) { bv = ov; bi = oi; }    \
    }                                                                \
    S = bv; I = bi; if (lane == bi) v = -1.f; }

__global__ __launch_bounds__(256) void k_router(const float* __restrict__ x,
    const float* __restrict__ Wr, const float* __restrict__ bias,
    int* __restrict__ cnt, int* __restrict__ lists, float* __restrict__ wlist) {
  __shared__ float part[4][RTB][64];
  __shared__ float logits[RTB][64];
  int t = threadIdx.x;
  int e = t & 63, sl = t >> 6;
  int tok0 = blockIdx.x * RTB;
  const float* xp = x + (size_t)tok0 * DM;
  float acc[RTB];
#pragma unroll
  for (int i = 0; i < RTB; ++i) acc[i] = 0.f;
  for (int d = sl * 512; d < sl * 512 + 512; ++d) {
    float w = Wr[(size_t)d * NEXP + e];
#pragma unroll
    for (int i = 0; i < RTB; ++i) acc[i] += xp[(size_t)i * DM + d] * w;
  }
#pragma unroll
  for (int i = 0; i < RTB; ++i) part[sl][i][e] = acc[i];
  __syncthreads();
  for (int i = sl; i < RTB; i += 4)
    logits[i][e] = part[0][i][e] + part[1][i][e] + part[2][i][e] + part[3][i][e] + bias[e];
  __syncthreads();
  int lane = t & 63, wv = t >> 6;
  for (int i = wv * 2; i < wv * 2 + 2; ++i) {
    float lg = logits[i][lane];
    float m = lg;
#pragma unroll
    for (int o = 32; o; o >>= 1) m = fmaxf(m, __shfl_xor(m, o));
    float p = expf(lg - m);
    float sm = p;
#pragma unroll
    for (int o = 32; o; o >>= 1) sm += __shfl_xor(sm, o);
    float v = p / sm;
    float s0, s1, s2, s3; int i0, i1, i2, i3;
    ARGMAX_ROUND(s0, i0)
    ARGMAX_ROUND(s1, i1)
    ARGMAX_ROUND(s2, i2)
    ARGMAX_ROUND(s3, i3)
    float tot = s0 + s1 + s2 + s3;
    if (lane < TOPK) {
      float myw = (lane == 0 ? s0 : lane == 1 ? s1 : lane == 2 ? s2 : s3) / tot;
      int   mye = (lane == 0 ? i0 : lane == 1 ? i1 : lane == 2 ? i2 : i3);
      int pos = atomicAdd(&cnt[mye], 1);
      if (pos < CAPC) {
        lists[mye * CAPC + pos] = tok0 + i;
        wlist[mye * CAPC + pos] = myw;
      }
    }
  }
}

// ---------------------------------------------------------------- offsets
__global__ void k_offs(const int* __restrict__ cnt, int* __restrict__ offs) {
  int l = threadIdx.x;            // 64 threads
  int c = min(cnt[l], CAPC);
  int sum = c;
#pragma unroll
  for (int o = 1; o < 64; o <<= 1) {
    int ov = __shfl_up(sum, o);
    if (l >= o) sum += ov;
  }
  offs[l + 1] = sum;
  if (l == 0) offs[0] = 0;
}

// ---------------------------------------------------------------- GEMM pieces
// LDS tiles: A [128][64] bf16 (row-major, 128B rows), B [64 n][64 k] bf16.
// XOR swizzle: byte ^= (row&7)<<4  (both write and read sides).
// Pipelined: LOAD(t+1) into regs is issued before MFMA(t) so VMEM stays busy.

template<bool GATHER>
static __device__ __forceinline__ void loadA(const unsigned short* __restrict__ src,
    int lda, int m0, int Mvalid, const int* __restrict__ gl, int k0, short8 (&r)[4]) {
  int tid = threadIdx.x;
#pragma unroll
  for (int p = 0; p < 4; ++p) {
    int idx = p * 256 + tid;
    int row = idx >> 3;
    int ko  = (idx & 7) * 8;
    int grow = m0 + row;
    if (grow < Mvalid) {
      int srow = GATHER ? gl[grow] : grow;
      r[p] = *(const short8*)(src + (size_t)srow * lda + k0 + ko);
    } else {
#pragma unroll
      for (int j = 0; j < 8; ++j) r[p][j] = 0;
    }
  }
}

static __device__ __forceinline__ void writeA(const short8 (&r)[4], unsigned short* lA) {
  int tid = threadIdx.x;
#pragma unroll
  for (int p = 0; p < 4; ++p) {
    int idx = p * 256 + tid;
    int row = idx >> 3;
    int ko  = (idx & 7) * 8;
    int byte = row * 128 + ko * 2;
    byte ^= (row & 7) << 4;
    *(short8*)((char*)lA + byte) = r[p];
  }
}

static __device__ __forceinline__ void loadB(const float* __restrict__ B, int ldb,
    int k0, int n0, f4 (&r)[4]) {
  int tid = threadIdx.x;
  int kb = tid >> 4;               // k block of 4
  int nb = tid & 15;               // n block of 4
  const float* p = B + (size_t)(k0 + kb * 4) * ldb + n0 + nb * 4;
#pragma unroll
  for (int q = 0; q < 4; ++q) r[q] = *(const f4*)(p + (size_t)q * ldb);
}

static __device__ __forceinline__ void writeB(const f4 (&r)[4], unsigned short* lB) {
  int tid = threadIdx.x;
  int kb = tid >> 4;
  int nb = tid & 15;
#pragma unroll
  for (int c = 0; c < 4; ++c) {
    short4v vv;
    vv[0] = (short)f2bf(r[0][c]); vv[1] = (short)f2bf(r[1][c]);
    vv[2] = (short)f2bf(r[2][c]); vv[3] = (short)f2bf(r[3][c]);
    int n = nb * 4 + c;
    int byte = n * 128 + kb * 8;
    byte ^= (n & 7) << 4;
    *(short4v*)((char*)lB + byte) = vv;
  }
}

static __device__ __forceinline__ short8 frag_ld(const unsigned short* lds, int row, int kElem) {
  int byte = row * 128 + kElem * 2;
  byte ^= (row & 7) << 4;
  return *(const short8*)((const char*)lds + byte);
}

static __device__ __forceinline__ void mma1(const unsigned short* lA, const unsigned short* lB,
    f32x4 (&acc)[4][2], int wm, int wn, int lane) {
  int r16 = lane & 15;
  int kg  = (lane >> 4) * 8;
#pragma unroll
  for (int kk = 0; kk < 2; ++kk) {
    int kb = kk * 32 + kg;
    short8 a[4], b[2];
#pragma unroll
    for (int mf = 0; mf < 4; ++mf) a[mf] = frag_ld(lA, wm + mf * 16 + r16, kb);
#pragma unroll
    for (int nf = 0; nf < 2; ++nf) b[nf] = frag_ld(lB, wn + nf * 16 + r16, kb);
#pragma unroll
    for (int mf = 0; mf < 4; ++mf)
#pragma unroll
      for (int nf = 0; nf < 2; ++nf)
        acc[mf][nf] = __builtin_amdgcn_mfma_f32_16x16x32_bf16(a[mf], b[nf], acc[mf][nf], 0, 0, 0);
  }
}

static __device__ __forceinline__ void mma2(const unsigned short* lA,
    const unsigned short* lBg, const unsigned short* lBu,
    f32x4 (&accg)[4][2], f32x4 (&accu)[4][2], int wm, int wn, int lane) {
  int r16 = lane & 15;
  int kg  = (lane >> 4) * 8;
#pragma unroll
  for (int kk = 0; kk < 2; ++kk) {
    int kb = kk * 32 + kg;
    short8 a[4], bg[2], bu[2];
#pragma unroll
    for (int mf = 0; mf < 4; ++mf) a[mf] = frag_ld(lA, wm + mf * 16 + r16, kb);
#pragma unroll
    for (int nf = 0; nf < 2; ++nf) {
      bg[nf] = frag_ld(lBg, wn + nf * 16 + r16, kb);
      bu[nf] = frag_ld(lBu, wn + nf * 16 + r16, kb);
    }
#pragma unroll
    for (int mf = 0; mf < 4; ++mf)
#pragma unroll
      for (int nf = 0; nf < 2; ++nf) {
        accg[mf][nf] = __builtin_amdgcn_mfma_f32_16x16x32_bf16(a[mf], bg[nf], accg[mf][nf], 0, 0, 0);
        accu[mf][nf] = __builtin_amdgcn_mfma_f32_16x16x32_bf16(a[mf], bu[nf], accu[mf][nf], 0, 0, 0);
      }
  }
}

static __device__ __forceinline__ float silu_mul(float g, float u) {
  return g / (1.f + expf(-g)) * u;
}

// ---------------------------------------------------------------- expert gate+up
__global__ __launch_bounds__(256) void k_expert_gateup(const unsigned short* __restrict__ xbf,
    const float* __restrict__ Wg, const float* __restrict__ Wu,
    const int* __restrict__ cnt, const int* __restrict__ offs,
    const int* __restrict__ lists, unsigned short* __restrict__ hws) {
  int e = blockIdx.y;
  int ne = min(cnt[e], CAPC);
  if (ne == 0) return;
  int n0 = blockIdx.x * 64;
  const float* Bg = Wg + (size_t)e * DM * HEXP;
  const float* Bu = Wu + (size_t)e * DM * HEXP;
  const int* lst = lists + e * CAPC;
  int base = offs[e];
  __shared__ unsigned short lA[128 * 64];
  __shared__ unsigned short lBg[64 * 64];
  __shared__ unsigned short lBu[64 * 64];
  int lane = threadIdx.x & 63, wv = threadIdx.x >> 6;
  int wm = (wv >> 1) * 64, wn = (wv & 1) * 32;
  for (int m0 = 0; m0 < ne; m0 += 128) {
    f32x4 accg[4][2] = {};
    f32x4 accu[4][2] = {};
    short8 ra[4]; f4 rg[4], ru[4];
    loadA<true>(xbf, DM, m0, ne, lst, 0, ra);
    loadB(Bg, HEXP, 0, n0, rg);
    loadB(Bu, HEXP, 0, n0, ru);
    for (int k0 = 0; k0 < DM; k0 += 64) {
      writeA(ra, lA);
      writeB(rg, lBg);
      writeB(ru, lBu);
      int kn = k0 + 64;
      if (kn < DM) {
        loadA<true>(xbf, DM, m0, ne, lst, kn, ra);
        loadB(Bg, HEXP, kn, n0, rg);
        loadB(Bu, HEXP, kn, n0, ru);
      }
      __syncthreads();
      mma2(lA, lBg, lBu, accg, accu, wm, wn, lane);
      __syncthreads();
    }
#pragma unroll
    for (int mf = 0; mf < 4; ++mf)
#pragma unroll
      for (int r = 0; r < 4; ++r) {
        int rl = m0 + wm + mf * 16 + (lane >> 4) * 4 + r;
        if (rl < ne) {
#pragma unroll
          for (int nf = 0; nf < 2; ++nf) {
            int col = n0 + wn + nf * 16 + (lane & 15);
            float h = silu_mul(accg[mf][nf][r], accu[mf][nf][r]);
            hws[(size_t)(base + rl) * HEXP + col] = f2bf(h);
          }
        }
      }
  }
}

// ---------------------------------------------------------------- shared gate+up
__global__ __launch_bounds__(256) void k_shared_gateup(const unsigned short* __restrict__ xbf,
    const float* __restrict__ Sg, const float* __restrict__ Su,
    unsigned short* __restrict__ hs) {
  int n0 = blockIdx.x * 64;
  int m0 = blockIdx.y * 128;
  int s  = blockIdx.z;
  const float* Bg = Sg + (size_t)s * DM * HSH;
  const float* Bu = Su + (size_t)s * DM * HSH;
  __shared__ unsigned short lA[128 * 64];
  __shared__ unsigned short lBg[64 * 64];
  __shared__ unsigned short lBu[64 * 64];
  int lane = threadIdx.x & 63, wv = threadIdx.x >> 6;
  int wm = (wv >> 1) * 64, wn = (wv & 1) * 32;
  f32x4 accg[4][2] = {};
  f32x4 accu[4][2] = {};
  short8 ra[4]; f4 rg[4], ru[4];
  loadA<false>(xbf, DM, m0, N_TOK, nullptr, 0, ra);
  loadB(Bg, HSH, 0, n0, rg);
  loadB(Bu, HSH, 0, n0, ru);
  for (int k0 = 0; k0 < DM; k0 += 64) {
    writeA(ra, lA);
    writeB(rg, lBg);
    writeB(ru, lBu);
    int kn = k0 + 64;
    if (kn < DM) {
      loadA<false>(xbf, DM, m0, N_TOK, nullptr, kn, ra);
      loadB(Bg, HSH, kn, n0, rg);
      loadB(Bu, HSH, kn, n0, ru);
    }
    __syncthreads();
    mma2(lA, lBg, lBu, accg, accu, wm, wn, lane);
    __syncthreads();
  }
#pragma unroll
  for (int mf = 0; mf < 4; ++mf)
#pragma unroll
    for (int nf = 0; nf < 2; ++nf)
#pragma unroll
      for (int r = 0; r < 4; ++r) {
        int row = m0 + wm + mf * 16 + (lane >> 4) * 4 + r;
        int col = n0 + wn + nf * 16 + (lane & 15);
        float h = silu_mul(accg[mf][nf][r], accu[mf][nf][r]);
        hs[(size_t)row * (NSH * HSH) + s * HSH + col] = f2bf(h);
      }
}

// ---------------------------------------------------------------- shared down (writes out)
__global__ __launch_bounds__(256) void k_shared_down(const unsigned short* __restrict__ hs,
    const float* __restrict__ Sd, float* __restrict__ out) {
  int n0 = blockIdx.x * 64;
  int m0 = blockIdx.y * 128;
  __shared__ unsigned short lA[128 * 64];
  __shared__ unsigned short lB[64 * 64];
  int lane = threadIdx.x & 63, wv = threadIdx.x >> 6;
  int wm = (wv >> 1) * 64, wn = (wv & 1) * 32;
  f32x4 acc[4][2] = {};
  short8 ra[4]; f4 rb[4];
  loadA<false>(hs, NSH * HSH, m0, N_TOK, nullptr, 0, ra);
  loadB(Sd, DM, 0, n0, rb);
  for (int k0 = 0; k0 < NSH * HSH; k0 += 64) {
    writeA(ra, lA);
    writeB(rb, lB);
    int kn = k0 + 64;
    if (kn < NSH * HSH) {
      loadA<false>(hs, NSH * HSH, m0, N_TOK, nullptr, kn, ra);
      loadB(Sd, DM, kn, n0, rb);
    }
    __syncthreads();
    mma1(lA, lB, acc, wm, wn, lane);
    __syncthreads();
  }
#pragma unroll
  for (int mf = 0; mf < 4; ++mf)
#pragma unroll
    for (int nf = 0; nf < 2; ++nf)
#pragma unroll
      for (int r = 0; r < 4; ++r) {
        int row = m0 + wm + mf * 16 + (lane >> 4) * 4 + r;
        int col = n0 + wn + nf * 16 + (lane & 15);
        out[(size_t)row * DM + col] = acc[mf][nf][r];
      }
}

// ---------------------------------------------------------------- expert down (atomic add)
__global__ __launch_bounds__(256) void k_expert_down(const unsigned short* __restrict__ hws,
    const float* __restrict__ Wd, const int* __restrict__ cnt, const int* __restrict__ offs,
    const int* __restrict__ lists, const float* __restrict__ wlist,
    float* __restrict__ out) {
  int e = blockIdx.y;
  int ne = min(cnt[e], CAPC);
  if (ne == 0) return;
  int n0 = blockIdx.x * 64;
  const float* B = Wd + (size_t)e * HEXP * DM;
  const unsigned short* A = hws + (size_t)offs[e] * HEXP;
  __shared__ unsigned short lA[128 * 64];
  __shared__ unsigned short lB[64 * 64];
  int lane = threadIdx.x & 63, wv = threadIdx.x >> 6;
  int wm = (wv >> 1) * 64, wn = (wv & 1) * 32;
  for (int m0 = 0; m0 < ne; m0 += 128) {
    f32x4 acc[4][2] = {};
    short8 ra[4]; f4 rb[4];
    loadA<false>(A, HEXP, m0, ne, nullptr, 0, ra);
    loadB(B, DM, 0, n0, rb);
    for (int k0 = 0; k0 < HEXP; k0 += 64) {
      writeA(ra, lA);
      writeB(rb, lB);
      int kn = k0 + 64;
      if (kn < HEXP) {
        loadA<false>(A, HEXP, m0, ne, nullptr, kn, ra);
        loadB(B, DM, kn, n0, rb);
      }
      __syncthreads();
      mma1(lA, lB, acc, wm, wn, lane);
      __syncthreads();
    }
#pragma unroll
    for (int mf = 0; mf < 4; ++mf)
#pragma unroll
      for (int r = 0; r < 4; ++r) {
        int rl = m0 + wm + mf * 16 + (lane >> 4) * 4 + r;
        if (rl < ne) {
          int tok  = lists[e * CAPC + rl];
          float w  = wlist[e * CAPC + rl];
#pragma unroll
          for (int nf = 0; nf < 2; ++nf) {
            int col = n0 + wn + nf * 16 + (lane & 15);
            atomicAdd(out + (size_t)tok * DM + col, acc[mf][nf][r] * w);
          }
        }
      }
  }
}

// ---------------------------------------------------------------- launch
extern "C" void kernel_launch(void* const* d_in, const int* in_sizes, int n_in,
                              void* d_out, int out_size, void* d_ws, size_t ws_size,
                              hipStream_t stream) {
  const float* x    = (const float*)d_in[0];
  const float* Wr   = (const float*)d_in[1];
  const float* bias = (const float*)d_in[2];
  const float* Wg   = (const float*)d_in[3];
  const float* Wu   = (const float*)d_in[4];
  const float* Wd   = (const float*)d_in[5];
  const float* Sg   = (const float*)d_in[6];
  const float* Su   = (const float*)d_in[7];
  const float* Sd   = (const float*)d_in[8];
  float* out = (float*)d_out;
  char* ws = (char*)d_ws;

  const size_t off_cnt   = 0;
  const size_t off_offs  = 256;
  const size_t off_lists = 1024;
  const size_t off_wlist = off_lists + (size_t)NEXP * CAPC * 4;
  const size_t off_xbf   = off_wlist + (size_t)NEXP * CAPC * 4;
  const size_t off_hs    = off_xbf + (size_t)N_TOK * DM * 2;
  const size_t off_h     = off_hs + (size_t)N_TOK * NSH * HSH * 2;
  const size_t req       = off_h + (size_t)N_TOK * TOPK * HEXP * 2;
  if (ws_size < req) return;   // loud failure, no corruption

  int* cnt            = (int*)(ws + off_cnt);
  int* offs           = (int*)(ws + off_offs);
  int* lists          = (int*)(ws + off_lists);
  float* wlist        = (float*)(ws + off_wlist);
  unsigned short* xbf = (unsigned short*)(ws + off_xbf);
  unsigned short* hs  = (unsigned short*)(ws + off_hs);
  unsigned short* hws = (unsigned short*)(ws + off_h);

  hipMemsetAsync(cnt, 0, NEXP * sizeof(int), stream);
  k_convert<<<(N_TOK * DM) / (256 * 8), 256, 0, stream>>>(x, xbf);
  k_router<<<N_TOK / RTB, 256, 0, stream>>>(x, Wr, bias, cnt, lists, wlist);
  k_offs<<<1, 64, 0, stream>>>(cnt, offs);
  k_expert_gateup<<<dim3(HEXP / 64, NEXP), 256, 0, stream>>>(xbf, Wg, Wu, cnt, offs, lists, hws);
  k_shared_gateup<<<dim3(HSH / 64, N_TOK / 128, NSH), 256, 0, stream>>>(xbf, Sg, Su, hs);
  k_shared_down<<<dim3(DM / 64, N_TOK / 128), 256, 0, stream>>>(hs, Sd, out);
  k_expert_down<<<dim3(DM / 64, NEXP), 256, 0, stream>>>(hws, Wd, cnt, offs, lists, wlist, out);
}